// Round 11
// baseline (104.897 us; speedup 1.0000x reference)
//
#include <hip/hip_runtime.h>
#include <hip/hip_bf16.h>
#include <math.h>

#define KW 5
#define BETA 15.0f
#define MSHIFT 3.0f
#define CIN 8
#define COUT 8
#define HH 256
#define WW 256
#define EXH 260                // padded image: row r holds h = r-2
#define EXW 260
#define EXPIX (EXH * EXW)      // 67600 px, 16 B each
#define PB 265                 // build_ex blocks per batch (265*256 >= 67600)
#define NG 8                   // K-groups: k=(tr 0..5, tc 0..4, c 0..7) pad 256
#define TWH 8                  // wave tile height (x16 px wide)

typedef float f32x4 __attribute__((ext_vector_type(4)));
typedef short s16x8 __attribute__((ext_vector_type(8)));

static __device__ __forceinline__ unsigned f2bf(float f) {
    unsigned u = __float_as_uint(f);
    return (u + 0x7FFFu + ((u >> 16) & 1u)) >> 16;  // RNE
}

// A-fragment table, exact MFMA A-layout, 2-ROW-PACKED (R9):
//   rows 0-7 : A[o][k=(tr,tc,c)] = exp(beta*w[o][c][tr,tc])    (0 at tr=5)
//   rows 8-15: A[8+o][k]         = exp(beta*w[o][c][tr-1,tc])  (0 at tr=0)
// D rows 0-7 = out row hl, rows 8-15 = out row hl+1. 512 entries, 8 KB.
__global__ void build_afrag(const float* __restrict__ wgt,
                            s16x8* __restrict__ table) {
    int i = blockIdx.x * 64 + threadIdx.x;       // 0..511
    int g = i >> 6, lane = i & 63;
    int quad = lane >> 4, row = lane & 15;
    int tap30 = g * 4 + quad;
    int tr = tap30 / KW, tc = tap30 % KW;
    s16x8 af;
    #pragma unroll
    for (int j = 0; j < CIN; ++j) {
        float v = 0.0f;
        if (tap30 < 30) {
            if (row < COUT) {
                if (tr <= 4)
                    v = __expf(BETA * wgt[(row * CIN + j) * (KW * KW) + tr * KW + tc]);
            } else {
                if (tr >= 1)
                    v = __expf(BETA * wgt[((row - 8) * CIN + j) * (KW * KW) + (tr - 1) * KW + tc]);
            }
        }
        af[j] = (short)f2bf(v);
    }
    table[i] = af;
}

// Pre-pass: EX[b][r][col] = 8 bf16 = exp(beta*(x-M)) channel-fastest, with a
// 2-px border holding exp(-beta*M) — the EXACT reference zero-pad term, so
// the main kernel needs no bounds logic at all. One exp per input element
// (8.39M total; R10's in-wave staging recomputed 15.7M with 1.88x halo).
// Swizzle matches morph: XCD k owns batches 2k,2k+1 -> EX written and read
// in the same XCD L2 (2.16 MB/XCD < 4 MB).
__global__ __launch_bounds__(256) void build_ex(
    const float* __restrict__ x, s16x8* __restrict__ ex)
{
    const int lid = blockIdx.x;               // 0..4239 = 8 XCD * 530
    const int sw  = (lid & 7) * 530 + (lid >> 3);
    const int b   = sw / PB;
    const int xb  = sw - b * PB;
    const int p   = xb * 256 + threadIdx.x;
    if (p >= EXPIX) return;
    const int r   = p / EXW, col = p - r * EXW;
    const int gh = r - 2, gw = col - 2;
    const bool ok = ((unsigned)gh < (unsigned)HH) & ((unsigned)gw < (unsigned)WW);
    unsigned pk[4];
    #pragma unroll
    for (int c2 = 0; c2 < 4; ++c2) {
        float v0 = 0.0f, v1 = 0.0f;
        if (ok) {
            v0 = x[((b * CIN + 2 * c2) * HH + gh) * WW + gw];
            v1 = x[((b * CIN + 2 * c2 + 1) * HH + gh) * WW + gw];
        }
        // exp(beta*(v-M)) = 2^(v*beta*log2e - beta*M*log2e)
        float2 e = make_float2(
            __builtin_amdgcn_exp2f(fmaf(v0, 21.6404256f, -64.9212768f)),
            __builtin_amdgcn_exp2f(fmaf(v1, 21.6404256f, -64.9212768f)));
        __hip_bfloat162 h2 = __float22bfloat162_rn(e);
        pk[c2] = *reinterpret_cast<unsigned*>(&h2);
    }
    int4 q; q.x = pk[0]; q.y = pk[1]; q.z = pk[2]; q.w = pk[3];
    *reinterpret_cast<int4*>(&ex[b * EXPIX + p]) = q;  // coalesced 16 B/lane
}

// Main: LDS-FREE implicit GEMM. B-fragment for lane (px,quad), group g:
// EX[b][h0+2hp+tr][w0+px+tc][0..7] — one global dwordx4; px-lanes give
// 256-B contiguous runs (4 runs/inst, L2-hot). 8 loads + 8 MFMA per
// hl-pair, hp groups independent -> deep VMEM/MFMA pipelining, no
// lgkmcnt chains, no barriers, no staging VALU.
// launch_bounds min-waves 6 -> ~85-VGPR cap (need ~75). NEVER 8: the
// 64-cap spilled afrag in R4/R5 (VGPR_Count 32, 2-4x hbm traffic).
__global__ __launch_bounds__(256, 6) void morph_mfma(
    const s16x8* __restrict__ ex, const s16x8* __restrict__ table,
    float* __restrict__ out)
{
    const int tid  = threadIdx.x;
    const int lane = tid & 63;
    const int wv   = tid >> 6;
    const int px   = lane & 15;
    const int quad = lane >> 4;

    // XCD-contiguous swizzle: 2048 blocks = 8 XCD * 256; XCD k gets b=2k,2k+1.
    const int lid = blockIdx.x;
    const int sw  = (lid & 7) * 256 + (lid >> 3);
    const int b   = sw >> 7;
    const int t   = sw & 127;                 // 32 h-tiles * 4 w-tiles
    const int h0  = (t >> 2) * TWH;
    const int w0  = (t & 3) * 64 + wv * 16;   // this wave's 16-px column

    // ---- A fragments: 8 coalesced 16-B loads (L2-hot table) ----
    s16x8 afrag[NG];
    int   toff[NG];
    #pragma unroll
    for (int g = 0; g < NG; ++g) {
        afrag[g] = table[g * 64 + lane];
        int tap30 = g * 4 + quad;
        int tcl   = tap30 < 30 ? tap30 : 29;  // clamp addr; A=0 kills pads
        toff[g] = (tcl / KW) * EXW + (tcl % KW);
    }

    const s16x8* exb = ex + b * EXPIX;
    const int base0 = h0 * EXW + w0 + px;     // EX-space: row h0+2hp+tr, col w0+px+tc

    const int dh = quad >> 1;                 // packed out row within pair
    const int ob = (quad & 1) * 4;            // o base for this quad
    const float LN2B = 0.04620981f;           // ln2 / beta
    #pragma unroll
    for (int hp = 0; hp < 4; ++hp) {
        const int rp = base0 + 2 * hp * EXW;
        f32x4 acc0 = {0.0f, 0.0f, 0.0f, 0.0f};
        f32x4 acc1 = {0.0f, 0.0f, 0.0f, 0.0f};
        #pragma unroll
        for (int g = 0; g < NG; ++g) {
            s16x8 bfr = exb[rp + toff[g]];    // global_load_dwordx4
            if (g & 1)
                acc1 = __builtin_amdgcn_mfma_f32_16x16x32_bf16(
                           afrag[g], bfr, acc1, 0, 0, 0);
            else
                acc0 = __builtin_amdgcn_mfma_f32_16x16x32_bf16(
                           afrag[g], bfr, acc0, 0, 0, 0);
        }
        const int h = h0 + 2 * hp + dh;
        #pragma unroll
        for (int r = 0; r < 4; ++r) {
            float s = acc0[r] + acc1[r];
            // out = M + log2(s) * ln2/beta   (v_log_f32 is log2)
            out[((b * COUT + ob + r) * HH + h) * WW + w0 + px]
                = fmaf(__builtin_amdgcn_logf(s), LN2B, MSHIFT);
        }
    }
}

extern "C" void kernel_launch(void* const* d_in, const int* in_sizes, int n_in,
                              void* d_out, int out_size, void* d_ws, size_t ws_size,
                              hipStream_t stream) {
    const float* x   = (const float*)d_in[0];
    const float* wgt = (const float*)d_in[1];
    float* out  = (float*)d_out;
    s16x8* tab  = (s16x8*)d_ws;                       // 8 KB
    s16x8* ex   = (s16x8*)((char*)d_ws + 8192);       // 16 * 67600 * 16 B

    const int B = in_sizes[0] / (CIN * HH * WW);      // 16
    build_afrag<<<NG, 64, 0, stream>>>(wgt, tab);
    build_ex<<<8 * 530, 256, 0, stream>>>(x, ex);     // 4240 blocks
    const int nblk = B * (HH / TWH) * (WW / 64);      // 2048
    morph_mfma<<<nblk, 256, 0, stream>>>(ex, tab, out);
}